// Round 4
// baseline (503.634 us; speedup 1.0000x reference)
//
#include <hip/hip_runtime.h>
#include <math.h>

#define NJ 24
#define COLN 14
#define MAPSZ 196           // 14*14
#define ROW (NJ*MAPSZ)      // 4704
#define NACC 25
#define TMPW 3

__device__ __constant__ int c_lengs[9][2][2] = {
  {{0,1},{5,6}}, {{1,2},{6,7}}, {{2,3},{7,8}}, {{2,4},{7,9}},
  {{15,16},{19,20}}, {{16,17},{20,21}}, {{17,18},{21,22}},
  {{0,23},{5,23}}, {{15,23},{19,23}}
};

// One block per batch row. Stages the 4704-float heatmap row in LDS,
// computes per-row argmax/gather/MSE/limb partials, writes 25 f32 partials.
__global__ __launch_bounds__(256) void loss_main(
    const float* __restrict__ o2D, const float* __restrict__ o3D,
    const float* __restrict__ h,   const float* __restrict__ dpt,
    const float* __restrict__ t2D, const float* __restrict__ t3D,
    const float* __restrict__ v,   float* __restrict__ partials, int B)
{
  __shared__ float sh[ROW];                 // 18816 B
  __shared__ float s_gx[NJ][COLN];
  __shared__ float s_gy[NJ][COLN];
  __shared__ int   s_mux[NJ], s_muy[NJ];
  __shared__ float s_v[NJ], s_vnew[NJ], s_place[NJ];
  __shared__ int   s_oob[NJ];
  __shared__ float s_t2d[NJ][2];
  __shared__ float s_t3d[NJ][3];
  __shared__ float s_x3d[NJ][3];
  __shared__ float s_jd2[NJ], s_jd3[NJ];
  __shared__ float s_limb0[9], s_limb1[9], s_vv[9];
  __shared__ float s_red[256];
  __shared__ float s_out[NACC];
  __shared__ int   s_anyoob;
  __shared__ int   s_dok;

  const int b   = blockIdx.x;
  const int tid = threadIdx.x;

  // ---- region 1: per-joint prep + stage h row into LDS ----
  if (tid < NJ) {
    int j = tid;
    float tx = t2D[((size_t)b*NJ + j)*2 + 0];
    float ty = t2D[((size_t)b*NJ + j)*2 + 1];
    float v0 = v[((size_t)b*NJ + j)*3 + 0];
    s_t2d[j][0] = tx; s_t2d[j][1] = ty;
    s_t3d[j][0] = t3D[((size_t)b*NJ + j)*3 + 0];
    s_t3d[j][1] = t3D[((size_t)b*NJ + j)*3 + 1];
    s_t3d[j][2] = t3D[((size_t)b*NJ + j)*3 + 2];
    s_v[j] = v0;
    // discrete decision: match JAX's mul-then-add f32 rounding (no FMA contraction)
    int mux = (int)floorf(__fadd_rn(__fmul_rn(tx, 14.0f), 0.5f));
    int muy = (int)floorf(__fadd_rn(__fmul_rn(ty, 14.0f), 0.5f));
    s_mux[j] = mux; s_muy[j] = muy;
    bool vis = (v0 == 1.0f);
    bool oob = vis && ((mux - TMPW >= COLN) || (muy - TMPW >= COLN) ||
                       (mux + TMPW + 1 <= 0) || (muy + TMPW + 1 <= 0));
    s_oob[j]   = oob ? 1 : 0;
    s_vnew[j]  = oob ? 0.0f : v0;
    s_place[j] = (vis && !oob) ? 1.0f : 0.0f;
  }
  if (tid == 0) s_dok = (dpt[b] > -990.0f) ? 1 : 0;
  {
    const float4* hp  = (const float4*)(h + (size_t)b * ROW);
    float4*       shp = (float4*)sh;
    for (int i = tid; i < ROW/4; i += 256) shp[i] = hp[i];
  }
  __syncthreads();

  // ---- region 2: separable gaussian tables (integer dx) + anyoob ----
  for (int i = tid; i < NJ*COLN; i += 256) {
    int j = i / COLN, x = i - j*COLN;
    int dx = x - s_mux[j];
    int dy = x - s_muy[j];
    s_gx[j][x] = (dx >= -TMPW && dx <= TMPW) ? expf(-0.5f * (float)(dx*dx)) : 0.0f;
    s_gy[j][x] = (dy >= -TMPW && dy <= TMPW) ? expf(-0.5f * (float)(dy*dy)) : 0.0f;
  }
  if (tid == 0) {
    int a = 0;
    #pragma unroll
    for (int j = 0; j < NJ; ++j) a |= s_oob[j];
    s_anyoob = a;
  }
  __syncthreads();

  // ---- region 3a: per-joint argmax (8 threads/joint) + issue gathers ----
  float g0=0.f,g1=0.f,g2=0.f,g3=0.f,g4=0.f;
  int   jj = -1, yC = 0, xC = 0;
  if (tid < NJ*8) {
    int j = tid >> 3, p = tid & 7;
    float best = -INFINITY; int bidx = 0;
    const float* hj = sh + j*MAPSZ;
    for (int idx = p; idx < MAPSZ; idx += 8) {
      float val = hj[idx];
      if (val > best) { best = val; bidx = idx; }   // first-max within subset
    }
    #pragma unroll
    for (int m = 1; m < 8; m <<= 1) {               // groups of 8 are wave-contiguous
      float ov = __shfl_xor(best, m);
      int   oi = __shfl_xor(bidx, m);
      if (ov > best || (ov == best && oi < bidx)) { best = ov; bidx = oi; }
    }
    if (p == 0) {
      jj = j;
      yC = bidx / COLN; xC = bidx - yC*COLN;
      size_t o2base = ((size_t)b*2*NJ + j)*MAPSZ + bidx;
      size_t o3base = ((size_t)b*3*NJ + j)*MAPSZ + bidx;
      g0 = o2D[o2base];
      g1 = o2D[o2base + (size_t)NJ*MAPSZ];
      g2 = o3D[o3base];
      g3 = o3D[o3base + (size_t)NJ*MAPSZ];
      g4 = o3D[o3base + (size_t)2*NJ*MAPSZ];
    }
  }

  // ---- region 3b: d1 masked-heatmap MSE (hides gather latency) ----
  float local1 = 0.0f;
  for (int i = tid; i < ROW; i += 256) {
    int j = i / MAPSZ;
    int r = i - j*MAPSZ;
    int y = r / COLN;
    int x = r - y*COLN;
    float tt   = s_gy[j][y] * s_gx[j][x];
    float diff = sh[i] - tt;
    local1 += s_place[j] * diff * diff;   // mask1 == place (v is 0/1)
  }

  // ---- region 3c: finish gather math (x2D/x3D, d2, d3 per joint) ----
  if (jj >= 0) {
    const float sc = 1.0f/14.0f;
    float x2_0 = g0 + (float)xC * sc;
    float x2_1 = g1 + (float)yC * sc;
    float dok  = s_dok ? 1.0f : 0.0f;
    float x3_0 = (g2 + (float)xC * sc) * dok;
    float x3_1 = (g3 + (float)yC * sc) * dok;
    float x3_2 = g4 * dok;
    s_x3d[jj][0] = x3_0; s_x3d[jj][1] = x3_1; s_x3d[jj][2] = x3_2;
    float vn  = s_vnew[jj];
    float d20 = (x2_0 - s_t2d[jj][0]) * vn;
    float d21 = (x2_1 - s_t2d[jj][1]) * vn;
    s_jd2[jj] = d20*d20 + d21*d21;
    float v3 = (s_dok && !s_anyoob) ? s_v[jj] : 0.0f;
    float e0 = (x3_0 - s_t3d[jj][0]) * v3;
    float e1 = (x3_1 - s_t3d[jj][1]) * v3;
    float e2 = (x3_2 - s_t3d[jj][2]) * v3;
    s_jd3[jj] = e0*e0 + e1*e1 + e2*e2;
  }
  __syncthreads();

  // ---- region 4: limb sums + block reduce of d1 ----
  if (tid < 9) {
    int k = tid;
    int i00 = c_lengs[k][0][0], i01 = c_lengs[k][0][1];
    int i10 = c_lengs[k][1][0], i11 = c_lengs[k][1][1];
    float vv = s_vnew[i00]*s_vnew[i01]*s_vnew[i10]*s_vnew[i11];
    float S0 = 0.f, S1 = 0.f;
    #pragma unroll
    for (int c = 0; c < 3; ++c) {
      float l0 = (s_x3d[i00][c] - s_x3d[i01][c]) * vv;
      float l1 = (s_x3d[i10][c] - s_x3d[i11][c]) * vv;
      S0 += l0*l0; S1 += l1*l1;
    }
    s_limb0[k] = S0; s_limb1[k] = S1; s_vv[k] = vv;
  }
  s_red[tid] = local1;
  __syncthreads();
  #pragma unroll
  for (int s = 128; s > 0; s >>= 1) {
    if (tid < s) s_red[tid] += s_red[tid + s];
    __syncthreads();
  }

  // ---- final: stage 25 partials in LDS, store in parallel ----
  if (tid == 0) {
    float sum2 = 0.f, N2 = 0.f, sum3 = 0.f, cnt = 0.f, Nv = 0.f, lengV = 0.f;
    #pragma unroll
    for (int j = 0; j < NJ; ++j) {
      sum2 += s_jd2[j]; N2 += s_vnew[j]; sum3 += s_jd3[j];
      cnt += s_place[j]; Nv += s_v[j];
    }
    float N3 = (s_dok && !s_anyoob) ? Nv : 0.0f;
    #pragma unroll
    for (int k = 0; k < 9; ++k) lengV += s_vv[k];
    s_out[0] = s_red[0];
    s_out[1] = cnt;
    s_out[2] = sum2;
    s_out[3] = N2;
    s_out[4] = sum3;
    s_out[5] = N3;
    s_out[6] = lengV;
    #pragma unroll
    for (int k = 0; k < 9; ++k) {
      s_out[7+k]  = s_limb0[k];
      s_out[16+k] = s_limb1[k];
    }
  }
  __syncthreads();
  if (tid < NACC) partials[(size_t)tid*B + b] = s_out[tid];
}

// Single-block final reduction in f64; applies the global sqrt for d4.
__global__ __launch_bounds__(256) void loss_reduce(
    const float* __restrict__ partials, float* __restrict__ out, int B)
{
  __shared__ double s_acc[NACC];
  int tid = threadIdx.x;
  int wave = tid >> 6, lane = tid & 63;
  for (int a = wave; a < NACC; a += 4) {
    double s = 0.0;
    for (int i = lane; i < B; i += 64) s += (double)partials[(size_t)a*B + i];
    #pragma unroll
    for (int m = 32; m >= 1; m >>= 1) s += __shfl_down(s, m);
    if (lane == 0) s_acc[a] = s;
  }
  __syncthreads();
  if (tid == 0) {
    double d1 = s_acc[0] / s_acc[1];
    double d2 = s_acc[2] / s_acc[3];
    double d3 = s_acc[4] / s_acc[5];
    double ll = 0.0;
    #pragma unroll
    for (int k = 0; k < 9; ++k) {
      double dl = sqrt(s_acc[7+k]) - sqrt(s_acc[16+k]);
      ll += dl*dl;
    }
    double d4 = ll / s_acc[6];
    out[0] = (float)(d1 + d2 + d3 + d4);
  }
}

extern "C" void kernel_launch(void* const* d_in, const int* in_sizes, int n_in,
                              void* d_out, int out_size, void* d_ws, size_t ws_size,
                              hipStream_t stream) {
  const float* o2D = (const float*)d_in[0];
  const float* o3D = (const float*)d_in[1];
  const float* h   = (const float*)d_in[2];
  const float* dpt = (const float*)d_in[3];
  const float* t2D = (const float*)d_in[4];
  const float* t3D = (const float*)d_in[5];
  const float* v   = (const float*)d_in[6];
  const int B = in_sizes[3];            // d has B elements
  float* partials = (float*)d_ws;       // NACC * B floats (400 KB)
  float* out = (float*)d_out;

  loss_main<<<B, 256, 0, stream>>>(o2D, o3D, h, dpt, t2D, t3D, v, partials, B);
  loss_reduce<<<1, 256, 0, stream>>>(partials, out, B);
}

// Round 5
// 498.886 us; speedup vs baseline: 1.0095x; 1.0095x over previous
//
#include <hip/hip_runtime.h>
#include <math.h>

#define NJ 24
#define COLN 14
#define MAPSZ 196           // 14*14
#define ROW (NJ*MAPSZ)      // 4704
#define NACC 25
#define TMPW 3

__device__ __constant__ int c_lengs[9][2][2] = {
  {{0,1},{5,6}}, {{1,2},{6,7}}, {{2,3},{7,8}}, {{2,4},{7,9}},
  {{15,16},{19,20}}, {{16,17},{20,21}}, {{17,18},{21,22}},
  {{0,23},{5,23}}, {{15,23},{19,23}}
};

// exp(-0.5*k^2) for k=0..3, correctly rounded f32 (only nonzero gaussian values)
__device__ __forceinline__ float gauss_of(int ad) {
  float g = 0.0f;
  g = (ad == 3) ? (float)0.011108996538242306 : g;
  g = (ad == 2) ? (float)0.1353352832366127   : g;
  g = (ad == 1) ? (float)0.6065306597126334   : g;
  g = (ad == 0) ? 1.0f                        : g;
  return g;
}

// One block per batch row. h row staged to LDS via global_load_lds DMA;
// wave 0 does per-joint prep + gaussian tables concurrently. 4 barriers total.
__global__ __launch_bounds__(256) void loss_main(
    const float* __restrict__ o2D, const float* __restrict__ o3D,
    const float* __restrict__ h,   const float* __restrict__ dpt,
    const float* __restrict__ t2D, const float* __restrict__ t3D,
    const float* __restrict__ v,   float* __restrict__ partials, int B)
{
  __shared__ float sh[ROW];                 // 18816 B
  __shared__ float s_gx[NJ][COLN];
  __shared__ float s_gy[NJ][COLN];
  __shared__ float s_v[NJ], s_vnew[NJ], s_place[NJ];
  __shared__ float s_t2d[NJ][2];
  __shared__ float s_t3d[NJ][3];
  __shared__ float s_x3d[NJ][3];
  __shared__ float s_jd2[NJ], s_jd3[NJ];
  __shared__ float s_limb0[9], s_limb1[9], s_vv[9];
  __shared__ float s_red4[4];
  __shared__ float s_out[NACC];
  __shared__ int   s_anyoob;
  __shared__ int   s_dok;

  const int b    = blockIdx.x;
  const int tid  = threadIdx.x;
  const int lane = tid & 63;
  const int w    = tid >> 6;

  // ---- issue LDS staging DMA first: overlaps wave-0 prep below ----
  // dest is wave-uniform base + lane*16 (global_load_lds semantics);
  // all bases are 16B-aligned (ROW*4 = 18816 = 1176*16).
  {
    const float* hrow = h + (size_t)b * ROW;
    #pragma unroll
    for (int k = 0; k < 4; ++k) {
      int base = k*1024 + w*256;            // float index, wave-uniform
      __builtin_amdgcn_global_load_lds(
        (const __attribute__((address_space(1))) void*)(hrow + base + lane*4),
        (__attribute__((address_space(3))) void*)(&sh[base]), 16, 0, 0);
    }
    int base = 4096 + w*256;                // tail: 608 floats
    if (base + lane*4 < ROW) {
      __builtin_amdgcn_global_load_lds(
        (const __attribute__((address_space(1))) void*)(hrow + base + lane*4),
        (__attribute__((address_space(3))) void*)(&sh[base]), 16, 0, 0);
    }
  }

  if (tid == 64) s_dok = (dpt[b] > -990.0f) ? 1 : 0;

  // ---- wave 0: per-joint prep + gaussian tables + oob ballot ----
  if (w == 0) {
    bool oob = false;
    if (tid < NJ) {
      int j = tid;
      float tx = t2D[((size_t)b*NJ + j)*2 + 0];
      float ty = t2D[((size_t)b*NJ + j)*2 + 1];
      float v0 = v[((size_t)b*NJ + j)*3 + 0];
      s_t2d[j][0] = tx; s_t2d[j][1] = ty;
      s_t3d[j][0] = t3D[((size_t)b*NJ + j)*3 + 0];
      s_t3d[j][1] = t3D[((size_t)b*NJ + j)*3 + 1];
      s_t3d[j][2] = t3D[((size_t)b*NJ + j)*3 + 2];
      s_v[j] = v0;
      // discrete decision: mul-then-add f32 rounding, no FMA contraction
      int mux = (int)floorf(__fadd_rn(__fmul_rn(tx, 14.0f), 0.5f));
      int muy = (int)floorf(__fadd_rn(__fmul_rn(ty, 14.0f), 0.5f));
      bool vis = (v0 == 1.0f);
      oob = vis && ((mux - TMPW >= COLN) || (muy - TMPW >= COLN) ||
                    (mux + TMPW + 1 <= 0) || (muy + TMPW + 1 <= 0));
      s_vnew[j]  = oob ? 0.0f : v0;
      s_place[j] = (vis && !oob) ? 1.0f : 0.0f;
      #pragma unroll
      for (int x = 0; x < COLN; ++x) {
        int dx = x - mux; int adx = dx < 0 ? -dx : dx;
        int dy = x - muy; int ady = dy < 0 ? -dy : dy;
        s_gx[j][x] = gauss_of(adx);
        s_gy[j][x] = gauss_of(ady);
      }
    }
    unsigned long long m = __ballot(oob);   // whole wave 0 participates
    if (lane == 0) s_anyoob = (m != 0ull) ? 1 : 0;
  }

  asm volatile("s_waitcnt vmcnt(0)" ::: "memory");  // drain LDS-DMA (insurance)
  __syncthreads();                                  // barrier 1

  // ---- argmax (8 threads/joint, waves 0-2) + issue the 5 gathers ----
  float g0=0.f,g1=0.f,g2=0.f,g3=0.f,g4=0.f;
  int   jj = -1, yC = 0, xC = 0;
  if (tid < NJ*8) {
    int j = tid >> 3, p = tid & 7;
    float best = -INFINITY; int bidx = 0;
    const float* hj = sh + j*MAPSZ;
    for (int idx = p; idx < MAPSZ; idx += 8) {
      float val = hj[idx];
      if (val > best) { best = val; bidx = idx; }   // first-max within subset
    }
    #pragma unroll
    for (int m = 1; m < 8; m <<= 1) {               // 8-groups are wave-contiguous
      float ov = __shfl_xor(best, m);
      int   oi = __shfl_xor(bidx, m);
      if (ov > best || (ov == best && oi < bidx)) { best = ov; bidx = oi; }
    }
    if (p == 0) {
      jj = j;
      yC = bidx / COLN; xC = bidx - yC*COLN;
      size_t o2base = ((size_t)b*2*NJ + j)*MAPSZ + bidx;
      size_t o3base = ((size_t)b*3*NJ + j)*MAPSZ + bidx;
      g0 = o2D[o2base];
      g1 = o2D[o2base + (size_t)NJ*MAPSZ];
      g2 = o3D[o3base];
      g3 = o3D[o3base + (size_t)NJ*MAPSZ];
      g4 = o3D[o3base + (size_t)2*NJ*MAPSZ];
    }
  }

  // ---- d1 MSE: thread tid<196 owns one (y,x) cell, loops j (no div/mod) ----
  float local1 = 0.0f;
  if (tid < MAPSZ) {
    int y = tid / COLN, x = tid - y*COLN;           // once per thread
    #pragma unroll
    for (int j = 0; j < NJ; ++j) {
      float tt   = s_gy[j][y] * s_gx[j][x];
      float diff = sh[j*MAPSZ + tid] - tt;
      local1 += s_place[j] * diff * diff;           // mask1 == place (v is 0/1)
    }
  }

  // ---- finish gather math (x2D/x3D, d2, d3 per joint) ----
  if (jj >= 0) {
    const float sc = 1.0f/14.0f;
    float x2_0 = g0 + (float)xC * sc;
    float x2_1 = g1 + (float)yC * sc;
    float dok  = s_dok ? 1.0f : 0.0f;
    float x3_0 = (g2 + (float)xC * sc) * dok;
    float x3_1 = (g3 + (float)yC * sc) * dok;
    float x3_2 = g4 * dok;
    s_x3d[jj][0] = x3_0; s_x3d[jj][1] = x3_1; s_x3d[jj][2] = x3_2;
    float vn  = s_vnew[jj];
    float d20 = (x2_0 - s_t2d[jj][0]) * vn;
    float d21 = (x2_1 - s_t2d[jj][1]) * vn;
    s_jd2[jj] = d20*d20 + d21*d21;
    float v3 = (s_dok && !s_anyoob) ? s_v[jj] : 0.0f;
    float e0 = (x3_0 - s_t3d[jj][0]) * v3;
    float e1 = (x3_1 - s_t3d[jj][1]) * v3;
    float e2 = (x3_2 - s_t3d[jj][2]) * v3;
    s_jd3[jj] = e0*e0 + e1*e1 + e2*e2;
  }
  __syncthreads();                                  // barrier 2

  // ---- limb sums (9 threads) + wave-level reduce of d1 ----
  if (tid < 9) {
    int k = tid;
    int i00 = c_lengs[k][0][0], i01 = c_lengs[k][0][1];
    int i10 = c_lengs[k][1][0], i11 = c_lengs[k][1][1];
    float vv = s_vnew[i00]*s_vnew[i01]*s_vnew[i10]*s_vnew[i11];
    float S0 = 0.f, S1 = 0.f;
    #pragma unroll
    for (int c = 0; c < 3; ++c) {
      float l0 = (s_x3d[i00][c] - s_x3d[i01][c]) * vv;
      float l1 = (s_x3d[i10][c] - s_x3d[i11][c]) * vv;
      S0 += l0*l0; S1 += l1*l1;
    }
    s_limb0[k] = S0; s_limb1[k] = S1; s_vv[k] = vv;
  }
  #pragma unroll
  for (int m = 1; m < 64; m <<= 1) local1 += __shfl_xor(local1, m);
  if (lane == 0) s_red4[w] = local1;
  __syncthreads();                                  // barrier 3

  // ---- combine + stage 25 partials, parallel store ----
  if (tid == 0) {
    float sum2 = 0.f, N2 = 0.f, sum3 = 0.f, cnt = 0.f, Nv = 0.f, lengV = 0.f;
    #pragma unroll
    for (int j = 0; j < NJ; ++j) {
      sum2 += s_jd2[j]; N2 += s_vnew[j]; sum3 += s_jd3[j];
      cnt += s_place[j]; Nv += s_v[j];
    }
    float N3 = (s_dok && !s_anyoob) ? Nv : 0.0f;
    #pragma unroll
    for (int k = 0; k < 9; ++k) lengV += s_vv[k];
    s_out[0] = s_red4[0] + s_red4[1] + s_red4[2] + s_red4[3];
    s_out[1] = cnt;
    s_out[2] = sum2;
    s_out[3] = N2;
    s_out[4] = sum3;
    s_out[5] = N3;
    s_out[6] = lengV;
    #pragma unroll
    for (int k = 0; k < 9; ++k) {
      s_out[7+k]  = s_limb0[k];
      s_out[16+k] = s_limb1[k];
    }
  }
  __syncthreads();                                  // barrier 4
  if (tid < NACC) partials[(size_t)tid*B + b] = s_out[tid];
}

// Single-block final reduction in f64; applies the global sqrt for d4.
__global__ __launch_bounds__(256) void loss_reduce(
    const float* __restrict__ partials, float* __restrict__ out, int B)
{
  __shared__ double s_acc[NACC];
  int tid = threadIdx.x;
  int wave = tid >> 6, lane = tid & 63;
  for (int a = wave; a < NACC; a += 4) {
    double s = 0.0;
    for (int i = lane; i < B; i += 64) s += (double)partials[(size_t)a*B + i];
    #pragma unroll
    for (int m = 32; m >= 1; m >>= 1) s += __shfl_down(s, m);
    if (lane == 0) s_acc[a] = s;
  }
  __syncthreads();
  if (tid == 0) {
    double d1 = s_acc[0] / s_acc[1];
    double d2 = s_acc[2] / s_acc[3];
    double d3 = s_acc[4] / s_acc[5];
    double ll = 0.0;
    #pragma unroll
    for (int k = 0; k < 9; ++k) {
      double dl = sqrt(s_acc[7+k]) - sqrt(s_acc[16+k]);
      ll += dl*dl;
    }
    double d4 = ll / s_acc[6];
    out[0] = (float)(d1 + d2 + d3 + d4);
  }
}

extern "C" void kernel_launch(void* const* d_in, const int* in_sizes, int n_in,
                              void* d_out, int out_size, void* d_ws, size_t ws_size,
                              hipStream_t stream) {
  const float* o2D = (const float*)d_in[0];
  const float* o3D = (const float*)d_in[1];
  const float* h   = (const float*)d_in[2];
  const float* dpt = (const float*)d_in[3];
  const float* t2D = (const float*)d_in[4];
  const float* t3D = (const float*)d_in[5];
  const float* v   = (const float*)d_in[6];
  const int B = in_sizes[3];            // d has B elements
  float* partials = (float*)d_ws;       // NACC * B floats (400 KB)
  float* out = (float*)d_out;

  loss_main<<<B, 256, 0, stream>>>(o2D, o3D, h, dpt, t2D, t3D, v, partials, B);
  loss_reduce<<<1, 256, 0, stream>>>(partials, out, B);
}